// Round 2
// baseline (7458.739 us; speedup 1.0000x reference)
//
#include <hip/hip_runtime.h>
#include <hip/hip_bf16.h>

constexpr int Bz = 32;     // batch
constexpr int Hd = 512;    // hidden
constexpr int Vv = 5000;   // vocab
constexpr int Tt = 38;     // caption length
constexpr int Ss = 37;     // outer iterations
constexpr int H3 = 1536;   // 3*H
constexpr int U  = 703;    // total sequential GRU steps = sum_{i=0}^{36}(i+1)
constexpr int RPB = 704;   // trajectory rows per batch (row 0 = pad -> one-hot col)
constexpr int Mrows = Bz * RPB;     // 22528
constexpr int OUTC = 704;
constexpr long long OUT_MAIN = (long long)Bz * Vv * OUTC;  // 112,640,000

typedef __attribute__((ext_vector_type(8))) short short8;   // 8 bf16
typedef __attribute__((ext_vector_type(4))) float floatx4;  // MFMA 16x16 C/D

__device__ __forceinline__ unsigned short f2bf(float f) {
    union { float f; unsigned int u; } x; x.f = f;
    unsigned int u = x.u;
    unsigned int r = u + 0x7FFFu + ((u >> 16) & 1u);  // RNE
    return (unsigned short)(r >> 16);
}

__global__ __launch_bounds__(256) void k_convert(const float* __restrict__ src,
                                                 unsigned short* __restrict__ dst, int n) {
    int i = blockIdx.x * 256 + threadIdx.x;
    if (i < n) dst[i] = f2bf(src[i]);
}

// E (s,b,h) bf16: s=0 -> embed[SOS], s>=1 -> embed[captions[b][s]]
__global__ __launch_bounds__(256) void k_embed(const float* __restrict__ tab,
                                               const int* __restrict__ cap,
                                               unsigned short* __restrict__ E, int n) {
    int i = blockIdx.x * 256 + threadIdx.x;
    if (i >= n) return;
    int h  = i & (Hd - 1);
    int sb = i >> 9;
    int b  = sb & 31;
    int s  = sb >> 5;
    int w  = (s == 0) ? 0 : cap[b * Tt + s];
    E[i] = f2bf(tab[w * Hd + h]);
}

// GI = E @ w_ih^T + b_ih   (M=1184, N=1536, K=512)
__global__ __launch_bounds__(256) void k_gemm_gi(const unsigned short* __restrict__ A,
                                                 const unsigned short* __restrict__ W,
                                                 const float* __restrict__ bias,
                                                 float* __restrict__ C) {
    constexpr int TM = (Ss * Bz) / 16;   // 74
    constexpr int TN = H3 / 16;          // 96
    int wid = blockIdx.x * 4 + (threadIdx.x >> 6);
    if (wid >= TM * TN) return;
    int tm = wid % TM, tn = wid / TM;
    int lane = threadIdx.x & 63;
    int col = lane & 15, quad = lane >> 4;

    const short8* Ap = (const short8*)(A + (size_t)(tm * 16 + col) * Hd + quad * 8);
    const short8* Wp = (const short8*)(W + (size_t)(tn * 16 + col) * Hd + quad * 8);
    floatx4 acc = {0.f, 0.f, 0.f, 0.f};
#pragma unroll
    for (int k = 0; k < 16; k++)
        acc = __builtin_amdgcn_mfma_f32_16x16x32_bf16(Ap[k * 4], Wp[k * 4], acc, 0, 0, 0);
    int n = tn * 16 + col;
    float bn = bias[n];
#pragma unroll
    for (int i = 0; i < 4; i++) {
        int m = tm * 16 + quad * 4 + i;
        C[m * H3 + n] = acc[i] + bn;
    }
}

// One GRU step of the 703-step chain.
// Ab: bf16 state rows (row b at Ab + b*astride), Hf: fp32 prev state (32x512).
// Writes fp32 next state (HfN) and bf16 trajectory row (ObU, row b at b*RPB*Hd).
__global__ __launch_bounds__(256) void k_step(const unsigned short* __restrict__ Ab, long astride,
                                              const float* __restrict__ Hf,
                                              const unsigned short* __restrict__ Whh,
                                              const float* __restrict__ GIs,
                                              const float* __restrict__ bhh,
                                              float* __restrict__ HfN,
                                              unsigned short* __restrict__ ObU) {
    int wid  = blockIdx.x * 4 + (threadIdx.x >> 6);  // 0..63
    int lane = threadIdx.x & 63;
    int mt = wid & 1, jt = wid >> 1;                 // mt: batch half, jt: 16-col group
    int col = lane & 15, quad = lane >> 4;
    int j = jt * 16 + col;

    const short8* Ap = (const short8*)(Ab + (size_t)(mt * 16 + col) * astride + quad * 8);
    const short8* Wr = (const short8*)(Whh + (size_t)j * Hd + quad * 8);
    const short8* Wz = (const short8*)(Whh + (size_t)(j + 512) * Hd + quad * 8);
    const short8* Wn = (const short8*)(Whh + (size_t)(j + 1024) * Hd + quad * 8);
    floatx4 aR = {0,0,0,0}, aZ = {0,0,0,0}, aN = {0,0,0,0};
#pragma unroll
    for (int k = 0; k < 16; k++) {
        short8 a = Ap[k * 4];
        aR = __builtin_amdgcn_mfma_f32_16x16x32_bf16(a, Wr[k * 4], aR, 0, 0, 0);
        aZ = __builtin_amdgcn_mfma_f32_16x16x32_bf16(a, Wz[k * 4], aZ, 0, 0, 0);
        aN = __builtin_amdgcn_mfma_f32_16x16x32_bf16(a, Wn[k * 4], aN, 0, 0, 0);
    }
    float br = bhh[j], bz = bhh[j + 512], bn = bhh[j + 1024];
#pragma unroll
    for (int i = 0; i < 4; i++) {
        int b = mt * 16 + quad * 4 + i;
        float ir  = GIs[b * H3 + j];
        float iz  = GIs[b * H3 + j + 512];
        float inn = GIs[b * H3 + j + 1024];
        float r = 1.f / (1.f + __expf(-(ir + aR[i] + br)));
        float z = 1.f / (1.f + __expf(-(iz + aZ[i] + bz)));
        float nn = tanhf(inn + r * (aN[i] + bn));
        float hp = Hf[b * Hd + j];
        float hn = (1.f - z) * nn + z * hp;
        HfN[b * Hd + j] = hn;
        ObU[(size_t)b * (RPB * Hd) + j] = f2bf(hn);
    }
}

// Projection: out[b][v][c] = Ob_row(b,c) . proj_w[v] + proj_b[v]; c=0 -> one-hot(v==0).
// A rows r = b*704 + c  (r%704==0 is pad). 128x128 tile, BK=32, scatter float4 epilogue.
__global__ __launch_bounds__(256) void k_proj(const unsigned short* __restrict__ A,
                                              const unsigned short* __restrict__ W,
                                              const float* __restrict__ pb,
                                              float* __restrict__ out) {
    __shared__ unsigned short As[128 * 40];   // +8 shorts pad per row: conflict-free b128
    __shared__ unsigned short Bs[128 * 40];
    int bx = blockIdx.x;
    int bn = bx % 40, bm = bx / 40;           // consecutive blocks share the A tile
    int m0 = bm * 128, n0 = bn * 128;
    int tid = threadIdx.x;
    int w = tid >> 6, lane = tid & 63;
    int wm = w & 1, wn = w >> 1;
    int col = lane & 15, quad = lane >> 4;

    floatx4 acc[4][4] = {};
    for (int kb = 0; kb < 16; ++kb) {
        int k0 = kb * 32;
        __syncthreads();
        for (int q = tid; q < 512; q += 256) {
            int row = q >> 2, kp = (q & 3) << 3;
            *(short8*)&As[row * 40 + kp] =
                *(const short8*)(A + (size_t)(m0 + row) * Hd + k0 + kp);
            int vr = n0 + row; if (vr >= Vv) vr = Vv - 1;
            *(short8*)&Bs[row * 40 + kp] =
                *(const short8*)(W + (size_t)vr * Hd + k0 + kp);
        }
        __syncthreads();
        short8 af[4], bf[4];
#pragma unroll
        for (int i = 0; i < 4; ++i) {
            af[i] = *(const short8*)&As[(wm * 64 + i * 16 + col) * 40 + quad * 8];
            bf[i] = *(const short8*)&Bs[(wn * 64 + i * 16 + col) * 40 + quad * 8];
        }
#pragma unroll
        for (int mi = 0; mi < 4; ++mi)
#pragma unroll
            for (int ni = 0; ni < 4; ++ni)
                acc[mi][ni] = __builtin_amdgcn_mfma_f32_16x16x32_bf16(af[mi], bf[ni],
                                                                      acc[mi][ni], 0, 0, 0);
    }
#pragma unroll
    for (int mi = 0; mi < 4; ++mi) {
        int r0l = m0 + wm * 64 + mi * 16 + quad * 4;  // aligned 4-row group, one b
        int b  = r0l / RPB;
        int cm = r0l - b * RPB;                       // multiple of 4
#pragma unroll
        for (int ni = 0; ni < 4; ++ni) {
            int v = n0 + wn * 64 + ni * 16 + col;
            if (v >= Vv) continue;
            float bias = pb[v];
            floatx4 a = acc[mi][ni];
            float4 val;
            val.x = a[0] + bias; val.y = a[1] + bias;
            val.z = a[2] + bias; val.w = a[3] + bias;
            if (cm == 0) val.x = (v == 0) ? 1.f : 0.f;   // fold one-hot column
            *(float4*)(out + ((size_t)(b * Vv + v)) * OUTC + cm) = val;
        }
    }
}

__global__ __launch_bounds__(256) void k_hidden(const float* __restrict__ src,
                                                float* __restrict__ out) {
    int i = blockIdx.x * 256 + threadIdx.x;
    if (i < Bz * Hd) out[i] = src[i];
}

extern "C" void kernel_launch(void* const* d_in, const int* in_sizes, int n_in,
                              void* d_out, int out_size, void* d_ws, size_t ws_size,
                              hipStream_t stream) {
    const float* img = (const float*)d_in[0];
    const int*   cap = (const int*)d_in[1];
    const float* tab = (const float*)d_in[2];
    const float* wih = (const float*)d_in[3];
    const float* whh = (const float*)d_in[4];
    const float* bih = (const float*)d_in[5];
    const float* bhh = (const float*)d_in[6];
    const float* pw  = (const float*)d_in[7];
    const float* pb  = (const float*)d_in[8];
    float* out = (float*)d_out;

    char* wp = (char*)d_ws;
    auto alloc = [&](size_t bytes) {
        char* p = wp;
        wp += (bytes + 511) & ~(size_t)511;
        return p;
    };
    unsigned short* Eb   = (unsigned short*)alloc((size_t)Ss * Bz * Hd * 2);
    unsigned short* wihb = (unsigned short*)alloc((size_t)H3 * Hd * 2);
    unsigned short* whhb = (unsigned short*)alloc((size_t)H3 * Hd * 2);
    unsigned short* pwb  = (unsigned short*)alloc((size_t)Vv * Hd * 2);
    unsigned short* imgb = (unsigned short*)alloc((size_t)Bz * Hd * 2);
    float*          GI   = (float*)alloc((size_t)Ss * Bz * H3 * 4);
    float*          Sf   = (float*)alloc((size_t)2 * Bz * Hd * 4);
    unsigned short* Ob   = (unsigned short*)alloc((size_t)Mrows * Hd * 2);

    k_convert<<<(H3 * Hd + 255) / 256, 256, 0, stream>>>(wih, wihb, H3 * Hd);
    k_convert<<<(H3 * Hd + 255) / 256, 256, 0, stream>>>(whh, whhb, H3 * Hd);
    k_convert<<<(Vv * Hd + 255) / 256, 256, 0, stream>>>(pw, pwb, Vv * Hd);
    k_convert<<<(Bz * Hd + 255) / 256, 256, 0, stream>>>(img, imgb, Bz * Hd);
    k_embed<<<(Ss * Bz * Hd + 255) / 256, 256, 0, stream>>>(tab, cap, Eb, Ss * Bz * Hd);

    k_gemm_gi<<<(74 * 96) / 4, 256, 0, stream>>>(Eb, wihb, bih, GI);

    // 703-step continuous GRU chain; s resets at each outer-iteration boundary.
    const unsigned short* ab = imgb;
    long astride = Hd;
    const float* hf = img;
    int i_it = 0, s_it = 0;
    for (int u = 0; u < U; ++u) {
        float* hfn = Sf + (size_t)(u & 1) * Bz * Hd;
        k_step<<<16, 256, 0, stream>>>(ab, astride, hf, whhb,
                                       GI + (size_t)s_it * Bz * H3, bhh,
                                       hfn, Ob + (size_t)(u + 1) * Hd);
        hf = hfn;
        ab = Ob + (size_t)(u + 1) * Hd;
        astride = (long)RPB * Hd;
        if (++s_it > i_it) { s_it = 0; ++i_it; }
    }

    k_proj<<<176 * 40, 256, 0, stream>>>(Ob, pwb, pb, out);
    k_hidden<<<(Bz * Hd + 255) / 256, 256, 0, stream>>>(Sf, out + OUT_MAIN);
}